// Round 4
// baseline (71.306 us; speedup 1.0000x reference)
//
#include <hip/hip_runtime.h>

// B=4096, IN_F=1024, NQ=4, L=2, C=256. R7 = R6 with the nontemporal
// builtin calls fixed to use clang ext_vector types (HIP_vector_type is
// rejected by __builtin_nontemporal_*).
//
// R5's verified closed form (Heisenberg / Pauli back-propagation, 10
// surviving terms) + per-c amortization: each thread handles FOUR batch
// rows for one c, so the w1-trig (8 transcendentals) and weight-only
// subproducts are computed once per 4 cells. Grid 4096->1024 workgroups.
// x/out are streaming (zero reuse) -> nontemporal load/store.
//
// Closed form (validated R5 against brute-force circuit sim, 6 configs
// exercising every term + identity + basis-flip chain):
//   a_q = x_q + w0_q ; C=cos a, S=sin a ; c=cos w1, s=sin w1
//   z0 = c1c2(c3 C0C1C3 + s3 S0S1S3) + s1s2(c3 C0S1S3 + s3 S0C1C3)
//   z1 = C3 (c0c1 C0C2 + s0s1 S0S2)
//   z2 = c0 (c1c2 C1C3 + s1s2 S1S3)
//   z3 = c1C0 (c0c2c3 C2 + s0s2s3 S2) + s1S0 (c0s2s3 C2 + s0c2c3 S2)

#define BQ 4096
#define CQ 256
#define ROWS 4   // batch rows per thread

typedef float f32x4 __attribute__((ext_vector_type(4)));

__global__ __launch_bounds__(256) void qsim_kernel(
    const float* __restrict__ x,
    const float* __restrict__ w,
    float* __restrict__ out)
{
    const int c  = threadIdx.x;                  // circuit index (blockDim==CQ)
    const int b0 = blockIdx.x * ROWS;            // first batch row of this block

    // ---- per-c (amortized over ROWS cells) ----
    const float4 w0 = reinterpret_cast<const float4*>(w)[c * 2 + 0];
    const float4 w1 = reinterpret_cast<const float4*>(w)[c * 2 + 1];

    const float c0 = __cosf(w1.x), s0 = __sinf(w1.x);
    const float c1 = __cosf(w1.y), s1 = __sinf(w1.y);
    const float c2 = __cosf(w1.z), s2 = __sinf(w1.z);
    const float c3 = __cosf(w1.w), s3 = __sinf(w1.w);

    const float c1c2 = c1 * c2, s1s2 = s1 * s2;
    const float c0c1 = c0 * c1, s0s1 = s0 * s1;
    const float G = c2 * c3, H = s2 * s3;        // z3 inner weights
    const float c0G = c0 * G, s0H = s0 * H;      // z3: c0c2c3, s0s2s3
    const float c0H = c0 * H, s0G = s0 * G;      // z3: c0s2s3, s0c2c3

    // ---- issue all ROWS x-loads up front (latency overlap) ----
    const f32x4* __restrict__ xv4 = reinterpret_cast<const f32x4*>(x);
    f32x4* __restrict__ ov4 = reinterpret_cast<f32x4*>(out);

    f32x4 xv[ROWS];
#pragma unroll
    for (int j = 0; j < ROWS; ++j)
        xv[j] = __builtin_nontemporal_load(xv4 + ((b0 + j) * CQ + c));

#pragma unroll
    for (int j = 0; j < ROWS; ++j) {
        // Fused embedding + layer-0: RX(w0)RX(x) = RX(x+w0).
        const float a0 = xv[j].x + w0.x;
        const float a1 = xv[j].y + w0.y;
        const float a2 = xv[j].z + w0.z;
        const float a3 = xv[j].w + w0.w;

        const float C0 = __cosf(a0), S0 = __sinf(a0);
        const float C1 = __cosf(a1), S1 = __sinf(a1);
        const float C2 = __cosf(a2), S2 = __sinf(a2);
        const float C3 = __cosf(a3), S3 = __sinf(a3);

        const float U = C1 * C3, V = S1 * S3;     // shared by z0, z2
        const float P = C0 * c3, Q = S0 * s3;     // z0

        // z0 = c1c2*(P*U + Q*V) + s1s2*(P*V + Q*U)
        const float z0 = fmaf(c1c2, fmaf(P, U, Q * V), s1s2 * fmaf(P, V, Q * U));
        // z1 = C3*(c0c1*C0C2 + s0s1*S0S2)
        const float z1 = C3 * fmaf(c0c1, C0 * C2, s0s1 * (S0 * S2));
        // z2 = c0*(c1c2*U + s1s2*V)
        const float z2 = c0 * fmaf(c1c2, U, s1s2 * V);
        // z3 = c1C0*(C2*c0G + S2*s0H) + s1S0*(C2*c0H + S2*s0G)
        const float z3 = fmaf(c1 * C0, fmaf(C2, c0G, S2 * s0H),
                              (s1 * S0) * fmaf(C2, c0H, S2 * s0G));

        f32x4 zv;
        zv.x = z0; zv.y = z1; zv.z = z2; zv.w = z3;
        __builtin_nontemporal_store(zv, ov4 + ((b0 + j) * CQ + c));
    }
}

extern "C" void kernel_launch(void* const* d_in, const int* in_sizes, int n_in,
                              void* d_out, int out_size, void* d_ws, size_t ws_size,
                              hipStream_t stream) {
    const float* x = (const float*)d_in[0];        // (4096, 1024) fp32
    const float* w = (const float*)d_in[1];        // (256, 2, 4) fp32
    float* out = (float*)d_out;                    // (4096, 1024) fp32

    qsim_kernel<<<BQ / ROWS, CQ, 0, stream>>>(x, w, out);
}

// Round 5
// 69.170 us; speedup vs baseline: 1.0309x; 1.0309x over previous
//
#include <hip/hip_runtime.h>
#include <math.h>

// B=4096, IN_F=1024, NQ=4, L=2, C=256. One thread = one (b,c) 4-qubit circuit.
//
// R8 = exact revert to R5 (best measured: 69.5 us). R7's ROWS=4 +
// nontemporal experiment was neutral-negative (71.3 us) and is dropped.
//
// Closed form via Heisenberg (Pauli back-propagation): push each measured
// Z_q backward through ring-2 CNOTs (Z-parity masks), layer-1 RX
// (Z -> c Z + s Y), ring-1 CNOTs (Clifford, compile-time), then evaluate
// on the product state RX(a_q)|0>: <Z>=cos a, <Y>=-sin a, <X>=0.
//
// Ring-1 conjugated generators (conjugation order C30,C23,C12,C01):
//   Z0->Z1Z2Z3  Z1->Z0Z1  Z2->Z0Z1Z2  Z3->Z0Z1Z2Z3
//   Y0->X0Y1Z2Z3  Y1->Z0Y1X2  Y2->Z0Z1Y2X3  Y3->-Y0Y1Z2Y3
// Multiplying per-term (with Pauli phases) and dropping X-carrying strings
// leaves TEN terms:
//   a_q = x_q + w0_q ; C=cos a, S=sin a ; c=cos w1, s=sin w1
//   z0 = c1c2(c3 C0C1C3 + s3 S0S1S3) + s1s2(c3 C0S1S3 + s3 S0C1C3)
//   z1 = C3 (c0c1 C0C2 + s0s1 S0S2)
//   z2 = c0 (c1c2 C1C3 + s1s2 S1S3)
//   z3 = c1C0 (c0c2c3 C2 + s0s2s3 S2) + s1S0 (c0s2s3 C2 + s0c2c3 S2)
// Validated against hand-simulated full circuit in 6 configurations that
// exercise every term individually, plus identity and basis-flip checks.
//
// Per-thread: 16 native trig + ~45 VALU -> HBM-bound (33.5 MB traffic,
// ~5.3 us floor; kernel ~6-7 us; remaining timed cost is the harness's
// 268 MB poison-fill (~44.4 us) + reset dispatches, fixed).

#define BQ 4096
#define CQ 256

__global__ __launch_bounds__(256) void qsim_kernel(
    const float* __restrict__ x,
    const float* __restrict__ w,
    float* __restrict__ out)
{
    const int tid = blockIdx.x * blockDim.x + threadIdx.x;   // [0, B*C)
    const int c = threadIdx.x;                               // blockDim == C == 256

    const float4 xv = reinterpret_cast<const float4*>(x)[tid];      // coalesced 16B
    const float4 w0 = reinterpret_cast<const float4*>(w)[c * 2 + 0]; // L1-resident 8KB
    const float4 w1 = reinterpret_cast<const float4*>(w)[c * 2 + 1];

    // Fused embedding + layer-0 full angles: RX(w0)RX(x) = RX(x+w0).
    const float a0 = xv.x + w0.x;
    const float a1 = xv.y + w0.y;
    const float a2 = xv.z + w0.z;
    const float a3 = xv.w + w0.w;

    const float C0 = __cosf(a0), S0 = __sinf(a0);
    const float C1 = __cosf(a1), S1 = __sinf(a1);
    const float C2 = __cosf(a2), S2 = __sinf(a2);
    const float C3 = __cosf(a3), S3 = __sinf(a3);

    // Layer-1 RX Heisenberg coefficients (full angles).
    const float c0 = __cosf(w1.x), s0 = __sinf(w1.x);
    const float c1 = __cosf(w1.y), s1 = __sinf(w1.y);
    const float c2 = __cosf(w1.z), s2 = __sinf(w1.z);
    const float c3 = __cosf(w1.w), s3 = __sinf(w1.w);

    // Shared subproducts.
    const float c1c2 = c1 * c2, s1s2 = s1 * s2;
    const float U = C1 * C3, V = S1 * S3;          // shared by z0, z2
    const float P = C0 * c3, Q = S0 * s3;          // z0

    // z0 = c1c2*(P*U + Q*V) + s1s2*(P*V + Q*U)
    const float z0 = fmaf(c1c2, fmaf(P, U, Q * V), s1s2 * fmaf(P, V, Q * U));
    // z1 = C3*(c0c1*C0C2 + s0s1*S0S2)
    const float z1 = C3 * fmaf(c0 * c1, C0 * C2, (s0 * s1) * (S0 * S2));
    // z2 = c0*(c1c2*U + s1s2*V)
    const float z2 = c0 * fmaf(c1c2, U, s1s2 * V);
    // z3 = c1C0*(E*G + F*H) + s1S0*(E*H + F*G),
    //   E = c0*C2, F = s0*S2, G = c2*c3, H = s2*s3
    const float E = c0 * C2, F = s0 * S2, G = c2 * c3, H = s2 * s3;
    const float z3 = fmaf(c1 * C0, fmaf(E, G, F * H), (s1 * S0) * fmaf(E, H, F * G));

    reinterpret_cast<float4*>(out)[tid] = make_float4(z0, z1, z2, z3);
}

extern "C" void kernel_launch(void* const* d_in, const int* in_sizes, int n_in,
                              void* d_out, int out_size, void* d_ws, size_t ws_size,
                              hipStream_t stream) {
    const float* x = (const float*)d_in[0];        // (4096, 1024) fp32
    const float* w = (const float*)d_in[1];        // (256, 2, 4) fp32
    float* out = (float*)d_out;                    // (4096, 1024) fp32

    const int total = BQ * CQ;                     // 1,048,576 threads
    qsim_kernel<<<total / 256, 256, 0, stream>>>(x, w, out);
}